// Round 1
// baseline (299.498 us; speedup 1.0000x reference)
//
#include <hip/hip_runtime.h>

// Problem constants (B, L, D from reference)
constexpr int Bn = 8;
constexpr int Ln = 4096;
constexpr int Dn = 768;
constexpr int CHUNKS = 64;          // L-chunks for column-sum kernel
constexpr int LC = Ln / CHUNKS;     // 64 rows per chunk

// ---------------------------------------------------------------------------
// K0: zero the accumulators in workspace (ws is poisoned to 0xAA every call)
// ---------------------------------------------------------------------------
__global__ void k_init(float* __restrict__ sumx, float* __restrict__ sumy) {
    int i = blockIdx.x * blockDim.x + threadIdx.x;
    if (i < Bn * Dn) sumx[i] = 0.0f;
    if (i < Bn)      sumy[i] = 0.0f;
}

// ---------------------------------------------------------------------------
// K1: column sums  sumx[b,d] = sum_l x[b,l,d]
// grid = Bn*CHUNKS blocks x 256 threads; each thread covers 3 d-values
// (D = 768 = 3*256); reads are coalesced (consecutive t -> consecutive d).
// ---------------------------------------------------------------------------
__global__ void k_colsum(const float* __restrict__ x, float* __restrict__ sumx) {
    int b = blockIdx.x / CHUNKS;
    int c = blockIdx.x % CHUNKS;
    int t = threadIdx.x;
    const float* xb = x + (size_t)b * Ln * Dn + (size_t)c * LC * Dn;
    float a0 = 0.f, a1 = 0.f, a2 = 0.f;
    for (int l = 0; l < LC; ++l) {
        const float* row = xb + (size_t)l * Dn;
        a0 += row[t];
        a1 += row[t + 256];
        a2 += row[t + 512];
    }
    atomicAdd(&sumx[b * Dn + t],       a0);
    atomicAdd(&sumx[b * Dn + t + 256], a1);
    atomicAdd(&sumx[b * Dn + t + 512], a2);
}

// ---------------------------------------------------------------------------
// K2: y[b,l] = (x[b,l,:] . sumx[b,:]) / (L*D)   (sumx holds the raw sum, so
//     dividing by L*D gives dot with the mean, divided by D)
//     Also accumulates sumy[b] += sum of this block's 4 y values.
// one wave (64 lanes) per row, 4 waves per block; D/4 = 192 float4 per row.
// ---------------------------------------------------------------------------
__global__ void k_rowdot(const float* __restrict__ x, const float* __restrict__ sumx,
                         float* __restrict__ y, float* __restrict__ sumy) {
    int wave = threadIdx.x >> 6;
    int lane = threadIdx.x & 63;
    int row  = blockIdx.x * 4 + wave;          // [0, B*L)
    int b    = row >> 12;                      // row / L

    const float4* xr = (const float4*)(x + (size_t)row * Dn);
    const float4* mv = (const float4*)(sumx + (size_t)b * Dn);

    float acc = 0.f;
    #pragma unroll
    for (int i = 0; i < Dn / 4 / 64; ++i) {    // 3 iterations
        float4 a = xr[lane + 64 * i];
        float4 m = mv[lane + 64 * i];
        acc += a.x * m.x + a.y * m.y + a.z * m.z + a.w * m.w;
    }
    #pragma unroll
    for (int off = 32; off >= 1; off >>= 1) acc += __shfl_down(acc, off);

    __shared__ float wsum[4];
    if (lane == 0) {
        float yv = acc * (1.0f / ((float)Ln * (float)Dn));
        y[row] = yv;
        wsum[wave] = yv;
    }
    __syncthreads();
    if (threadIdx.x == 0) {
        float s = wsum[0] + wsum[1] + wsum[2] + wsum[3];
        atomicAdd(&sumy[b], s);                // all 4 rows share the same b
    }
}

// ---------------------------------------------------------------------------
// K3: out[b,l,d] = alpha[l] + (y[b,l] * sumy[b] / L^2) * x[b,l,d]
// one block (192 threads = 3 waves) per row; each thread one float4.
// ---------------------------------------------------------------------------
__global__ void k_epilogue(const float* __restrict__ x, const float* __restrict__ y,
                           const float* __restrict__ sumy, const float* __restrict__ alpha,
                           float* __restrict__ out) {
    int row = blockIdx.x;          // [0, B*L)
    int b   = row >> 12;
    int l   = row & (Ln - 1);
    int t   = threadIdx.x;         // [0, 192)

    float coef = y[row] * sumy[b] * (1.0f / ((float)Ln * (float)Ln));
    float a    = alpha[l];

    const float4* xr = (const float4*)(x + (size_t)row * Dn);
    float4*       orow = (float4*)(out + (size_t)row * Dn);

    float4 v = xr[t];
    float4 o;
    o.x = a + coef * v.x;
    o.y = a + coef * v.y;
    o.z = a + coef * v.z;
    o.w = a + coef * v.w;
    orow[t] = o;
}

// ---------------------------------------------------------------------------
extern "C" void kernel_launch(void* const* d_in, const int* in_sizes, int n_in,
                              void* d_out, int out_size, void* d_ws, size_t ws_size,
                              hipStream_t stream) {
    const float* x     = (const float*)d_in[0];   // [B, L, D]
    const float* alpha = (const float*)d_in[1];   // [L, 1]
    float* out = (float*)d_out;                   // [B, L, D]

    // workspace layout: sumx[B*D] | sumy[B] | y[B*L]
    float* sumx = (float*)d_ws;
    float* sumy = sumx + Bn * Dn;
    float* y    = sumy + Bn;

    k_init<<<(Bn * Dn + 255) / 256, 256, 0, stream>>>(sumx, sumy);
    k_colsum<<<Bn * CHUNKS, 256, 0, stream>>>(x, sumx);
    k_rowdot<<<(Bn * Ln) / 4, 256, 0, stream>>>(x, sumx, y, sumy);
    k_epilogue<<<Bn * Ln, 192, 0, stream>>>(x, y, sumy, alpha, out);
}

// Round 2
// 197.093 us; speedup vs baseline: 1.5196x; 1.5196x over previous
//
#include <hip/hip_runtime.h>

constexpr int Bn = 8;
constexpr int Ln = 4096;
constexpr int Dn = 768;
constexpr int CHUNKS = 64;              // row-chunks per batch for partial colsum
constexpr int RPC = Ln / CHUNKS;        // 64 rows per chunk

// ---------------------------------------------------------------------------
// K1: partial column sums (no atomics).
// grid = Bn*CHUNKS blocks x 192 threads; thread t owns float4-column t.
// Each wave issues 64 independent 1KB-coalesced float4 loads -> HBM-bound.
// part[b][c][d] = sum over the chunk's 64 rows.
// ---------------------------------------------------------------------------
__global__ void k_colsum_part(const float* __restrict__ x, float4* __restrict__ part) {
    int b = blockIdx.x / CHUNKS;
    int c = blockIdx.x % CHUNKS;
    int t = threadIdx.x;                 // 0..191 (D/4 = 192)
    const float4* xb = (const float4*)(x + ((size_t)b * Ln + (size_t)c * RPC) * Dn);
    float4 s = {0.f, 0.f, 0.f, 0.f};
    for (int l = 0; l < RPC; ++l) {
        float4 v = xb[(size_t)l * (Dn / 4) + t];
        s.x += v.x; s.y += v.y; s.z += v.z; s.w += v.w;
    }
    part[((size_t)b * CHUNKS + c) * (Dn / 4) + t] = s;
}

// ---------------------------------------------------------------------------
// K2: fold partials -> colsum, then m[b,d] = colsum[b,d] * ||colsum_b||^2 / (L^4 D^2).
// Derivation: y_l = x_l.colsum/(L D); sum_y = ||colsum||^2/(L D);
//             coef_l = y_l * sum_y / L^2 = x_l . m  with m as above.
// grid = Bn blocks x 256 threads (thread t owns d = t, t+256, t+512).
// ---------------------------------------------------------------------------
__global__ void k_scale(const float* __restrict__ part, float* __restrict__ m) {
    int b = blockIdx.x;
    int t = threadIdx.x;                 // 0..255
    const float* pb = part + (size_t)b * CHUNKS * Dn;
    float s0 = 0.f, s1 = 0.f, s2 = 0.f;
    for (int c = 0; c < CHUNKS; ++c) {
        const float* row = pb + (size_t)c * Dn;
        s0 += row[t];
        s1 += row[t + 256];
        s2 += row[t + 512];
    }
    float ssq = s0 * s0 + s1 * s1 + s2 * s2;
    // butterfly over 64 lanes, then LDS across the 4 waves
    #pragma unroll
    for (int off = 1; off < 64; off <<= 1) ssq += __shfl_xor(ssq, off);
    __shared__ float wsum[4];
    int wave = t >> 6, lane = t & 63;
    if (lane == 0) wsum[wave] = ssq;
    __syncthreads();
    float ss = wsum[0] + wsum[1] + wsum[2] + wsum[3];

    const float f1 = 1.0f / ((float)Ln * (float)Dn);          // 1/(L*D)
    float scale = ss * f1 * f1 / ((float)Ln * (float)Ln);     // ||cs||^2/(L^4 D^2)
    m[b * Dn + t]       = s0 * scale;
    m[b * Dn + t + 256] = s1 * scale;
    m[b * Dn + t + 512] = s2 * scale;
}

// ---------------------------------------------------------------------------
// K3: fused rowdot + epilogue. One wave per row; x stays in registers for
// both the dot and the write-back. No atomics, no LDS, no __syncthreads.
// out[b,l,d] = alpha[l] + (x_row . m_b) * x[b,l,d]
// ---------------------------------------------------------------------------
__global__ void k_fused(const float* __restrict__ x, const float* __restrict__ m,
                        const float* __restrict__ alpha, float* __restrict__ out) {
    int wave = threadIdx.x >> 6;
    int lane = threadIdx.x & 63;
    int row  = blockIdx.x * 4 + wave;    // [0, B*L)
    int b    = row >> 12;
    int l    = row & (Ln - 1);

    const float4* xr = (const float4*)(x + (size_t)row * Dn);
    const float4* mr = (const float4*)(m + (size_t)b * Dn);

    float4 x0 = xr[lane], x1 = xr[lane + 64], x2 = xr[lane + 128];
    float4 m0 = mr[lane], m1 = mr[lane + 64], m2 = mr[lane + 128];

    float acc = x0.x * m0.x + x0.y * m0.y + x0.z * m0.z + x0.w * m0.w
              + x1.x * m1.x + x1.y * m1.y + x1.z * m1.z + x1.w * m1.w
              + x2.x * m2.x + x2.y * m2.y + x2.z * m2.z + x2.w * m2.w;
    // butterfly: every lane ends with the full row dot
    #pragma unroll
    for (int off = 1; off < 64; off <<= 1) acc += __shfl_xor(acc, off);

    float a = alpha[l];
    float4* orow = (float4*)(out + (size_t)row * Dn);
    float4 o0 = {a + acc * x0.x, a + acc * x0.y, a + acc * x0.z, a + acc * x0.w};
    float4 o1 = {a + acc * x1.x, a + acc * x1.y, a + acc * x1.z, a + acc * x1.w};
    float4 o2 = {a + acc * x2.x, a + acc * x2.y, a + acc * x2.z, a + acc * x2.w};
    orow[lane]       = o0;
    orow[lane + 64]  = o1;
    orow[lane + 128] = o2;
}

// ---------------------------------------------------------------------------
extern "C" void kernel_launch(void* const* d_in, const int* in_sizes, int n_in,
                              void* d_out, int out_size, void* d_ws, size_t ws_size,
                              hipStream_t stream) {
    const float* x     = (const float*)d_in[0];   // [B, L, D]
    const float* alpha = (const float*)d_in[1];   // [L, 1]
    float* out = (float*)d_out;                   // [B, L, D]

    // ws layout: part[B*CHUNKS*D] | m[B*D]   (~1.6 MB total)
    float* part = (float*)d_ws;
    float* m    = part + (size_t)Bn * CHUNKS * Dn;

    k_colsum_part<<<Bn * CHUNKS, 192, 0, stream>>>(x, (float4*)part);
    k_scale<<<Bn, 256, 0, stream>>>(part, m);
    k_fused<<<(Bn * Ln) / 4, 256, 0, stream>>>(x, m, alpha, out);
}